// Round 17
// baseline (15515.376 us; speedup 1.0000x reference)
//
#include <hip/hip_runtime.h>
#include <math.h>

#define Bsz 512
#define Tsz 1024
#define Vsz 27
#define Hsz 512
#define BH (Bsz * Hsz)
#define TV (Tsz * Vsz)
#define NBLK 256
#define NT 512
#define JB 32        // blocks per bt-group (consensus barrier)

typedef float f32x4 __attribute__((ext_vector_type(4)));
typedef short s16x8 __attribute__((ext_vector_type(8)));
typedef unsigned int u32x4 __attribute__((ext_vector_type(4)));
#define MFMA __builtin_amdgcn_mfma_f32_16x16x32_bf16

// ws byte offsets
#define WS_CNT  ((size_t)2 * 3 * BH * 2)             // consensus counters (4KB)
#define WS_FLG  (WS_CNT + 4096)                      // 256KB per-wave flags
#define WS_DSTG (WS_FLG + 262144)                    // 32KB decode stream
#define WS_WXG  (WS_DSTG + (size_t)2 * 16 * 512 * 2) // 192KB x-fold W stream

__device__ __forceinline__ unsigned short btrunc(float x) {   // bf16 RTZ bits
    return (unsigned short)(__float_as_uint(x) >> 16);
}
__device__ __forceinline__ float bup(unsigned short b) {
    return __uint_as_float(((unsigned)b) << 16);
}
__device__ __forceinline__ unsigned short brne(float x) {     // bf16 RNE bits
    unsigned u = __float_as_uint(x);
    return (unsigned short)((u + 0x7FFFu + ((u >> 16) & 1u)) >> 16);
}
__device__ __forceinline__ __amdgpu_buffer_rsrc_t make_rsrc(void* p, unsigned bytes) {
    return __builtin_amdgcn_make_buffer_rsrc(p, (short)0, (int)bytes, 0x00020000);
}
template<bool FAST>
__device__ __forceinline__ s16x8 loadA(__amdgpu_buffer_rsrc_t r, int off) {
    u32x4 d = __builtin_amdgcn_raw_buffer_load_b128(r, off, 0, FAST ? 0 : 0x11);
    return __builtin_bit_cast(s16x8, d);
}
template<bool FAST>
__device__ __forceinline__ void storeH(__amdgpu_buffer_rsrc_t r, int off, unsigned short v) {
    __builtin_amdgcn_raw_buffer_store_b16(v, r, off, 0, FAST ? 0 : 0x11);
}
// per-wave flags (128B-strided), PROVEN primitives (__hip_atomic_*, agent)
__device__ __forceinline__ unsigned* flag_ptr(unsigned* flags, int bt, int m, int jp) {
    return flags + (size_t)((((bt << 3) + m) << 5) + jp) * 32;
}
__device__ __forceinline__ unsigned flag_get(unsigned* p) {
    return __hip_atomic_load(p, __ATOMIC_RELAXED, __HIP_MEMORY_SCOPE_AGENT);
}
__device__ __forceinline__ void gate2(unsigned* flags, int bt, int m, int c, int step) {
    unsigned* fA = flag_ptr(flags, bt, m, c << 1);
    unsigned* fB = fA + 32;
    while ((int)flag_get(fA) < step || (int)flag_get(fB) < step)
        __builtin_amdgcn_s_sleep(2);
}

// 6-product triple-split fp32-grade MFMA (R7-R16 proven)
#define PROD6(ACC, B1_, B2_, B3_, A1_, A2_, A3_) do { \
    ACC = MFMA(A1_, B1_, ACC, 0, 0, 0); \
    ACC = MFMA(A1_, B2_, ACC, 0, 0, 0); \
    ACC = MFMA(A2_, B1_, ACC, 0, 0, 0); \
    ACC = MFMA(A1_, B3_, ACC, 0, 0, 0); \
    ACC = MFMA(A2_, B2_, ACC, 0, 0, 0); \
    ACC = MFMA(A3_, B1_, ACC, 0, 0, 0); } while (0)
#define PROD5(ACC, B1_, B2_, A1_, A2_, A3_) do { \
    ACC = MFMA(A1_, B1_, ACC, 0, 0, 0); \
    ACC = MFMA(A1_, B2_, ACC, 0, 0, 0); \
    ACC = MFMA(A2_, B1_, ACC, 0, 0, 0); \
    ACC = MFMA(A2_, B2_, ACC, 0, 0, 0); \
    ACC = MFMA(A3_, B1_, ACC, 0, 0, 0); } while (0)

__global__ void init_ws_kernel(unsigned short* __restrict__ hpl, unsigned* __restrict__ cntr,
                               unsigned short* __restrict__ Dstg, unsigned short* __restrict__ Wxg,
                               const float* __restrict__ W_ih, const float* __restrict__ W_dec)
{
    size_t gid = (size_t)blockIdx.x * 256 + threadIdx.x;
    size_t gsz = (size_t)gridDim.x * 256;
    for (size_t i = gid; i < (size_t)(2 * 3 * BH * 2) / 16; i += gsz)
        ((uint4*)hpl)[i] = make_uint4(0u, 0u, 0u, 0u);
    // zero consensus counters + per-wave flags (4KB + 256KB = 66560 uints)
    for (size_t i = gid; i < 66560; i += gsz) cntr[i] = 0u;
    // decode stream [jj:2][c:16][lane:64][8]
    for (size_t i = gid; i < 2 * 16 * 512; i += gsz) {
        int e = i & 7, ln2 = (i >> 3) & 63, c = (i >> 9) & 15, jj = (int)(i >> 13);
        int cc2 = ln2 & 15, qq2 = ln2 >> 4;
        int k = c * 32 + qq2 * 8 + e;
        int vr = jj * 16 + cc2;
        Dstg[i] = (vr < Vsz) ? brne(W_dec[(size_t)vr * Hsz + k]) : (unsigned short)0;
    }
    // x-fold W stream [grow:1536][p:2][k:32]
    for (size_t i = gid; i < 1536 * 64; i += gsz) {
        int k = i & 31, p = (i >> 5) & 1, grow = (int)(i >> 6);
        float v = (k < Vsz) ? W_ih[grow * Vsz + k] : 0.f;
        unsigned short t1 = btrunc(v); float r1 = v - bup(t1);
        unsigned short t2 = btrunc(r1);
        Wxg[i] = p ? t2 : t1;
    }
}

// atomic group barrier — used ONCE for the XCD-consensus pre-barrier (proven)
__device__ __forceinline__ void group_barrier(unsigned* c, unsigned target) {
    __syncthreads();
    if (threadIdx.x == 0) {
        __hip_atomic_fetch_add(c, 1u, __ATOMIC_RELAXED, __HIP_MEMORY_SCOPE_AGENT);
        while (__hip_atomic_load(c, __ATOMIC_RELAXED, __HIP_MEMORY_SCOPE_AGENT) < target)
            __builtin_amdgcn_s_sleep(2);
    }
    __syncthreads();
}

// One fully wave-autonomous chain: 8 batch rows x 16 h' cols, all 3 gates.
// NO __syncthreads anywhere in the loop — 8 chains per block overlap freely.
template<bool FAST>
__device__ __forceinline__ void gru_loop(
    const float* __restrict__ x, float* __restrict__ out,
    const unsigned short* __restrict__ Dstg, const unsigned short* __restrict__ Wxg,
    unsigned* __restrict__ flags, __amdgpu_buffer_rsrc_t hrs,
    const unsigned short* Bst,
    float bih_r, float bih_z, float bih_n,
    float bhh_r, float bhh_z, float bhh_n, float bdv,
    int tid, int bt, int j, int b0, int g0)
{
    const int w = tid >> 6, ln = tid & 63;
    const int m = w;                       // 8-row slice 0..7
    const int cc = ln & 15, qq = ln >> 4;
    const int arow = b0 + (m << 3) + (cc & 7);   // A rows 8-15 duplicate 0-7
    const int rowBase = (arow * Hsz + (qq << 3)) << 1;   // bytes
    unsigned* myflag = flag_ptr(flags, bt, m, j);
    const int vcol = (j << 4) + cc;

    float hk[4] = {0.f, 0.f, 0.f, 0.f};

    for (int i = 0; i <= Tsz; ++i) {
        if (FAST) asm volatile("buffer_inv" ::: "memory");   // drop stale L1 lines
        // x for THIS step straight to regs (hidden under the K-loop)
        float xreg[8];
        if (i < Tsz) {
            #pragma unroll
            for (int e = 0; e < 8; ++e) {
                int k = (qq << 3) + e;
                xreg[e] = (k < Vsz) ? x[(size_t)arow * TV + (size_t)i * Vsz + k] : 0.f;
            }
        }
        const int voffA0 = (i & 1) * (3 * BH * 2) + rowBase;

        f32x4 accR = {0,0,0,0}, accZ = {0,0,0,0}, accNh = {0,0,0,0};
        f32x4 accNi = {0,0,0,0}, accD = {0,0,0,0};

        // 3-slot A pipeline over 16 chunks, producer-gated (R16-proven pattern)
        s16x8 A1s[3], A2s[3], A3s[3];
        gate2(flags, bt, m, 0, i);
        A1s[0] = loadA<FAST>(hrs, voffA0);
        A2s[0] = loadA<FAST>(hrs, voffA0 + BH * 2);
        A3s[0] = loadA<FAST>(hrs, voffA0 + 2 * BH * 2);
        gate2(flags, bt, m, 1, i);
        A1s[1] = loadA<FAST>(hrs, voffA0 + 64);
        A2s[1] = loadA<FAST>(hrs, voffA0 + 64 + BH * 2);
        A3s[1] = loadA<FAST>(hrs, voffA0 + 64 + 2 * BH * 2);
        unsigned pfa = flag_get(flag_ptr(flags, bt, m, 4));
        unsigned pfb = flag_get(flag_ptr(flags, bt, m, 5));
        #pragma unroll
        for (int c = 0; c < 16; ++c) {
            if (c + 2 < 16) {
                if ((int)pfa < i || (int)pfb < i) gate2(flags, bt, m, c + 2, i);
                const int s2 = (c + 2) % 3;
                A1s[s2] = loadA<FAST>(hrs, voffA0 + (c + 2) * 64);
                A2s[s2] = loadA<FAST>(hrs, voffA0 + (c + 2) * 64 + BH * 2);
                A3s[s2] = loadA<FAST>(hrs, voffA0 + (c + 2) * 64 + 2 * BH * 2);
                if (c + 3 < 16) {
                    pfa = flag_get(flag_ptr(flags, bt, m, (c + 3) << 1));
                    pfb = flag_get(flag_ptr(flags, bt, m, ((c + 3) << 1) + 1));
                }
            }
            const int sl = c % 3;
            s16x8 A1 = A1s[sl], A2 = A2s[sl], A3 = A3s[sl];
            const unsigned short* bs = Bst + (size_t)(c * 9) * 512 + (ln << 3);
            {   // r gate
                s16x8 B1 = *(const s16x8*)(bs);
                s16x8 B2 = *(const s16x8*)(bs + 512);
                s16x8 B3 = *(const s16x8*)(bs + 1024);
                PROD6(accR, B1, B2, B3, A1, A2, A3);
            }
            {   // z gate
                s16x8 C1 = *(const s16x8*)(bs + 1536);
                s16x8 C2 = *(const s16x8*)(bs + 2048);
                s16x8 C3 = *(const s16x8*)(bs + 2560);
                PROD6(accZ, C1, C2, C3, A1, A2, A3);
            }
            {   // n gate (h part)
                s16x8 N1 = *(const s16x8*)(bs + 3072);
                s16x8 N2 = *(const s16x8*)(bs + 3584);
                s16x8 N3 = *(const s16x8*)(bs + 4096);
                PROD6(accNh, N1, N2, N3, A1, A2, A3);
            }
            if (j < 2) {   // fused decode of h_i (this wave's rows, v-tile j)
                s16x8 D1 = *(const s16x8*)(Dstg + (size_t)((j << 4) + c) * 512 + (ln << 3));
                accD = MFMA(A1, D1, accD, 0, 0, 0);
                accD = MFMA(A2, D1, accD, 0, 0, 0);
            }
        }

        // x-fold: triple-split fp32 x from regs, 2-plane W from global stream
        if (i < Tsz) {
            s16x8 A1, A2, A3;
            #pragma unroll
            for (int e = 0; e < 8; ++e) {
                float v = xreg[e];
                unsigned short s1 = btrunc(v); float r1 = v - bup(s1);
                unsigned short s2 = btrunc(r1); float r2 = r1 - bup(s2);
                unsigned short s3 = btrunc(r2);
                A1[e] = (short)s1; A2[e] = (short)s2; A3[e] = (short)s3;
            }
            {
                const unsigned short* wb = Wxg + (size_t)(g0 + cc) * 64 + (qq << 3);
                s16x8 B1 = *(const s16x8*)(wb);
                s16x8 B2 = *(const s16x8*)(wb + 32);
                PROD5(accR, B1, B2, A1, A2, A3);
            }
            {
                const unsigned short* wb = Wxg + (size_t)(Hsz + g0 + cc) * 64 + (qq << 3);
                s16x8 B1 = *(const s16x8*)(wb);
                s16x8 B2 = *(const s16x8*)(wb + 32);
                PROD5(accZ, B1, B2, A1, A2, A3);
            }
            {
                const unsigned short* wb = Wxg + (size_t)(2 * Hsz + g0 + cc) * 64 + (qq << 3);
                s16x8 B1 = *(const s16x8*)(wb);
                s16x8 B2 = *(const s16x8*)(wb + 32);
                PROD5(accNi, B1, B2, A1, A2, A3);
            }
        }

        // epilogue: rows qq*4+r (valid 0..7 -> qq<2 lanes), cols g0+cc
        if (i < Tsz && qq < 2) {
            const int wpar = ((i + 1) & 1) * (3 * BH * 2);
            #pragma unroll
            for (int r = 0; r < 4; ++r) {
                float rv = accR[r] + bih_r + bhh_r;
                float zv = accZ[r] + bih_z + bhh_z;
                float nh = accNh[r] + bhh_n;
                float ni = accNi[r] + bih_n;
                float rg = 1.f / (1.f + expf(-rv));
                float zg = 1.f / (1.f + expf(-zv));
                float ng = tanhf(ni + rg * nh);
                float hv = (1.f - zg) * ng + zg * hk[r];
                hk[r] = hv;
                int brow = b0 + (m << 3) + (qq << 2) + r;
                int e2 = wpar + ((brow * Hsz + g0 + cc) << 1);
                unsigned short s1 = btrunc(hv); float r1 = hv - bup(s1);
                unsigned short s2 = btrunc(r1); float r2 = r1 - bup(s2);
                unsigned short s3 = btrunc(r2);
                storeH<FAST>(hrs, e2, s1);
                storeH<FAST>(hrs, e2 + BH * 2, s2);
                storeH<FAST>(hrs, e2 + 2 * BH * 2, s3);
            }
        }
        if (i < Tsz) {
            // per-wave publish: h stores drained, and flag also certifies this
            // wave finished reading h_i (gates covered all 32 producers)
            asm volatile("s_waitcnt vmcnt(0)" ::: "memory");
            if (ln == 0)
                __hip_atomic_store(myflag, (unsigned)(i + 1), __ATOMIC_RELAXED,
                                   __HIP_MEMORY_SCOPE_AGENT);
        }
        // logits[:, i-1, :] from h_i (after publish; off critical path)
        if (i > 0 && j < 2 && qq < 2 && vcol < Vsz) {
            #pragma unroll
            for (int r = 0; r < 4; ++r) {
                size_t brow = (size_t)(b0 + (m << 3) + (qq << 2) + r);
                out[brow * TV + (size_t)(i - 1) * Vsz + vcol] = accD[r] + bdv;
            }
        }
    }
}

__global__ __launch_bounds__(NT, 2) void gru_persist(
    const float* __restrict__ x, const float* __restrict__ W_ih,
    const float* __restrict__ W_hh, const float* __restrict__ b_ih,
    const float* __restrict__ b_hh, const float* __restrict__ W_dec,
    const float* __restrict__ b_dec, char* __restrict__ wsb,
    float* __restrict__ out)
{
    __shared__ unsigned short Bst[16 * 9 * 512];   // [c][tile*plane][lane][8] 144KB
    __shared__ int fastFlag;

    unsigned short* hpl = (unsigned short*)wsb;
    unsigned* cbase = (unsigned*)(wsb + WS_CNT);
    unsigned* flags = (unsigned*)(wsb + WS_FLG);
    unsigned short* Dstg = (unsigned short*)(wsb + WS_DSTG);
    unsigned short* Wxg  = (unsigned short*)(wsb + WS_WXG);

    const int tid = threadIdx.x;
    const int bt  = blockIdx.x & 7;     // group == XCD if round-robin holds
    const int j   = blockIdx.x >> 3;    // 0..31 (16 h' cols)
    const int b0  = bt * 64;
    const int g0  = j * 16;
    unsigned* pcnt  = cbase + 16 + bt;        // consensus barrier counter
    unsigned* xmask = cbase + 32 + bt;        // XCD-id mask

    // ---- one-time: B-stream (triple-split W_hh, fragment-linear) ----
    for (int idx = tid; idx < 16 * 9 * 512; idx += NT) {
        int e = idx & 7, ln2 = (idx >> 3) & 63, s = idx >> 9;
        int p = s % 3, t = (s / 3) % 3, c = s / 9;
        int cc2 = ln2 & 15, qq2 = ln2 >> 4;
        int k = c * 32 + qq2 * 8 + e;
        int grow = t * Hsz + g0 + cc2;
        float v = W_hh[(size_t)grow * Hsz + k];
        unsigned short t1 = btrunc(v); float r1 = v - bup(t1);
        unsigned short t2 = btrunc(r1); float r2 = r1 - bup(t2);
        unsigned short t3 = btrunc(r2);
        Bst[idx] = (p == 0) ? t1 : (p == 1) ? t2 : t3;
    }
    // ---- XCD consensus: fast path iff whole group on one XCD ----
    if (tid == 0) {
        unsigned xcc;
        asm volatile("s_getreg_b32 %0, hwreg(20, 0, 32)" : "=s"(xcc));
        __hip_atomic_fetch_or(xmask, 1u << (xcc & 31), __ATOMIC_RELAXED,
                              __HIP_MEMORY_SCOPE_AGENT);
        asm volatile("s_waitcnt vmcnt(0)" ::: "memory");
    }
    group_barrier(pcnt, JB);
    if (tid == 0) {
        unsigned f = __hip_atomic_load(xmask, __ATOMIC_RELAXED, __HIP_MEMORY_SCOPE_AGENT);
        fastFlag = (__popc(f) == 1) ? 1 : 0;
    }
    __syncthreads();   // Bst ready + consensus decided (last sync before loop)
    const bool fastv = (fastFlag != 0);

    const int cc = tid & 15;
    const float bih_r = b_ih[g0 + cc];
    const float bih_z = b_ih[Hsz + g0 + cc];
    const float bih_n = b_ih[2 * Hsz + g0 + cc];
    const float bhh_r = b_hh[g0 + cc];
    const float bhh_z = b_hh[Hsz + g0 + cc];
    const float bhh_n = b_hh[2 * Hsz + g0 + cc];
    const int vcol = (j << 4) + cc;
    const float bdv = (j < 2 && vcol < Vsz) ? b_dec[vcol] : 0.f;
    __amdgpu_buffer_rsrc_t hrs = make_rsrc((void*)hpl, (unsigned)(2u * 3u * BH * 2u));

    if (fastv)
        gru_loop<true>(x, out, Dstg, Wxg, flags, hrs, Bst,
                       bih_r, bih_z, bih_n, bhh_r, bhh_z, bhh_n, bdv,
                       tid, bt, j, b0, g0);
    else
        gru_loop<false>(x, out, Dstg, Wxg, flags, hrs, Bst,
                        bih_r, bih_z, bih_n, bhh_r, bhh_z, bhh_n, bdv,
                        tid, bt, j, b0, g0);
}

extern "C" void kernel_launch(void* const* d_in, const int* in_sizes, int n_in,
                              void* d_out, int out_size, void* d_ws, size_t ws_size,
                              hipStream_t stream) {
    const float* x     = (const float*)d_in[0];
    const float* W_ih  = (const float*)d_in[1];
    const float* W_hh  = (const float*)d_in[2];
    const float* b_ih  = (const float*)d_in[3];
    const float* b_hh  = (const float*)d_in[4];
    const float* W_dec = (const float*)d_in[5];
    const float* b_dec = (const float*)d_in[6];
    float* out = (float*)d_out;
    char* wsb  = (char*)d_ws;

    init_ws_kernel<<<768, 256, 0, stream>>>(
        (unsigned short*)wsb, (unsigned*)(wsb + WS_CNT),
        (unsigned short*)(wsb + WS_DSTG), (unsigned short*)(wsb + WS_WXG),
        W_ih, W_dec);

    // Plain launch: 144 KB LDS -> 1 block/CU, grid == 256 == CU count ->
    // all blocks co-resident. Per-wave producer-flag dataflow cannot
    // deadlock: flags monotonic, every wave publishes after every step
    // (induction: step-i gates need only step-(i-1) publishes).
    gru_persist<<<dim3(NBLK), dim3(NT), 0, stream>>>(
        x, W_ih, W_hh, b_ih, b_hh, W_dec, b_dec, wsb, out);
}

// Round 18
// 12026.015 us; speedup vs baseline: 1.2902x; 1.2902x over previous
//
#include <hip/hip_runtime.h>
#include <math.h>

#define Bsz 512
#define Tsz 1024
#define Vsz 27
#define Hsz 512
#define BH (Bsz * Hsz)
#define TV (Tsz * Vsz)
#define NBLK 256
#define NT 256       // 4 waves; wave = 16 distinct batch rows, all 3 gates
#define JB 32        // blocks per bt-group

typedef float f32x4 __attribute__((ext_vector_type(4)));
typedef short s16x8 __attribute__((ext_vector_type(8)));
typedef unsigned int u32x4 __attribute__((ext_vector_type(4)));
#define MFMA __builtin_amdgcn_mfma_f32_16x16x32_bf16

// ws byte offsets
#define WS_CNT  ((size_t)2 * 3 * BH * 2)             // consensus counters (4KB)
#define WS_FLG  (WS_CNT + 4096)                      // 128KB per-wave flags
#define WS_DSTG (WS_FLG + 262144)                    // 32KB decode stream
#define WS_WXG  (WS_DSTG + (size_t)2 * 16 * 512 * 2) // 192KB x-fold W stream

__device__ __forceinline__ unsigned short btrunc(float x) {   // bf16 RTZ bits
    return (unsigned short)(__float_as_uint(x) >> 16);
}
__device__ __forceinline__ float bup(unsigned short b) {
    return __uint_as_float(((unsigned)b) << 16);
}
__device__ __forceinline__ unsigned short brne(float x) {     // bf16 RNE bits
    unsigned u = __float_as_uint(x);
    return (unsigned short)((u + 0x7FFFu + ((u >> 16) & 1u)) >> 16);
}
__device__ __forceinline__ __amdgpu_buffer_rsrc_t make_rsrc(void* p, unsigned bytes) {
    return __builtin_amdgcn_make_buffer_rsrc(p, (short)0, (int)bytes, 0x00020000);
}
template<bool FAST>
__device__ __forceinline__ s16x8 loadA(__amdgpu_buffer_rsrc_t r, int off) {
    u32x4 d = __builtin_amdgcn_raw_buffer_load_b128(r, off, 0, FAST ? 0 : 0x11);
    return __builtin_bit_cast(s16x8, d);
}
template<bool FAST>
__device__ __forceinline__ void storeH(__amdgpu_buffer_rsrc_t r, int off, unsigned short v) {
    __builtin_amdgcn_raw_buffer_store_b16(v, r, off, 0, FAST ? 0 : 0x11);
}
// per-wave flags (128B-strided): (bt,m,j) -> slot. PROVEN __hip_atomic_* only.
__device__ __forceinline__ unsigned* flag_ptr(unsigned* flags, int bt, int m, int jp) {
    return flags + (size_t)((((bt << 2) + m) << 5) + jp) * 32;
}

// Interleaved 6-product triple-split for 3 gates: per-accumulator order is
// A1B1,A1B2,A2B1,A1B3,A2B2,A3B1 — identical to R7-R17's proven PROD6.
// Distance-3 between same-acc MFMAs tolerates dependent-MFMA latency at 1 wave/SIMD.
#define TRI6(AR, AZ, AN, R1,R2,R3, Z1,Z2,Z3, N1,N2,N3, A1_,A2_,A3_) do { \
    AR = MFMA(A1_, R1, AR,0,0,0); AZ = MFMA(A1_, Z1, AZ,0,0,0); AN = MFMA(A1_, N1, AN,0,0,0); \
    AR = MFMA(A1_, R2, AR,0,0,0); AZ = MFMA(A1_, Z2, AZ,0,0,0); AN = MFMA(A1_, N2, AN,0,0,0); \
    AR = MFMA(A2_, R1, AR,0,0,0); AZ = MFMA(A2_, Z1, AZ,0,0,0); AN = MFMA(A2_, N1, AN,0,0,0); \
    AR = MFMA(A1_, R3, AR,0,0,0); AZ = MFMA(A1_, Z3, AZ,0,0,0); AN = MFMA(A1_, N3, AN,0,0,0); \
    AR = MFMA(A2_, R2, AR,0,0,0); AZ = MFMA(A2_, Z2, AZ,0,0,0); AN = MFMA(A2_, N2, AN,0,0,0); \
    AR = MFMA(A3_, R1, AR,0,0,0); AZ = MFMA(A3_, Z1, AZ,0,0,0); AN = MFMA(A3_, N1, AN,0,0,0); \
} while (0)
#define TRI5(AR, AZ, AN, R1,R2, Z1,Z2, N1,N2, A1_,A2_,A3_) do { \
    AR = MFMA(A1_, R1, AR,0,0,0); AZ = MFMA(A1_, Z1, AZ,0,0,0); AN = MFMA(A1_, N1, AN,0,0,0); \
    AR = MFMA(A1_, R2, AR,0,0,0); AZ = MFMA(A1_, Z2, AZ,0,0,0); AN = MFMA(A1_, N2, AN,0,0,0); \
    AR = MFMA(A2_, R1, AR,0,0,0); AZ = MFMA(A2_, Z1, AZ,0,0,0); AN = MFMA(A2_, N1, AN,0,0,0); \
    AR = MFMA(A2_, R2, AR,0,0,0); AZ = MFMA(A2_, Z2, AZ,0,0,0); AN = MFMA(A2_, N2, AN,0,0,0); \
    AR = MFMA(A3_, R1, AR,0,0,0); AZ = MFMA(A3_, Z1, AZ,0,0,0); AN = MFMA(A3_, N1, AN,0,0,0); \
} while (0)

__global__ void init_ws_kernel(unsigned short* __restrict__ hpl, unsigned* __restrict__ cntr,
                               unsigned short* __restrict__ Dstg, unsigned short* __restrict__ Wxg,
                               const float* __restrict__ W_ih, const float* __restrict__ W_dec)
{
    size_t gid = (size_t)blockIdx.x * 256 + threadIdx.x;
    size_t gsz = (size_t)gridDim.x * 256;
    for (size_t i = gid; i < (size_t)(2 * 3 * BH * 2) / 16; i += gsz)
        ((uint4*)hpl)[i] = make_uint4(0u, 0u, 0u, 0u);
    // zero consensus counters + per-wave flags (4KB + 128KB)
    for (size_t i = gid; i < 33792; i += gsz) cntr[i] = 0u;
    // decode stream [jj:2][c:16][lane:64][8]
    for (size_t i = gid; i < 2 * 16 * 512; i += gsz) {
        int e = i & 7, ln2 = (i >> 3) & 63, c = (i >> 9) & 15, jj = (int)(i >> 13);
        int cc2 = ln2 & 15, qq2 = ln2 >> 4;
        int k = c * 32 + qq2 * 8 + e;
        int vr = jj * 16 + cc2;
        Dstg[i] = (vr < Vsz) ? brne(W_dec[(size_t)vr * Hsz + k]) : (unsigned short)0;
    }
    // x-fold W stream [grow:1536][p:2][k:32]
    for (size_t i = gid; i < 1536 * 64; i += gsz) {
        int k = i & 31, p = (i >> 5) & 1, grow = (int)(i >> 6);
        float v = (k < Vsz) ? W_ih[grow * Vsz + k] : 0.f;
        unsigned short t1 = btrunc(v); float r1 = v - bup(t1);
        unsigned short t2 = btrunc(r1);
        Wxg[i] = p ? t2 : t1;
    }
}

// atomic group barrier — used ONCE for the XCD-consensus pre-barrier (proven)
__device__ __forceinline__ void group_barrier(unsigned* c, unsigned target) {
    __syncthreads();
    if (threadIdx.x == 0) {
        __hip_atomic_fetch_add(c, 1u, __ATOMIC_RELAXED, __HIP_MEMORY_SCOPE_AGENT);
        while (__hip_atomic_load(c, __ATOMIC_RELAXED, __HIP_MEMORY_SCOPE_AGENT) < target)
            __builtin_amdgcn_s_sleep(2);
    }
    __syncthreads();
}

// Fully wave-autonomous chain: 16 distinct batch rows x 16 h' cols, 3 gates.
// No __syncthreads in the loop; ONE ballot-gate per step; all A-loads upfront.
template<bool FAST>
__device__ __forceinline__ void gru_loop(
    const float* __restrict__ x, float* __restrict__ out,
    const unsigned short* __restrict__ Dstg, const unsigned short* __restrict__ Wxg,
    unsigned* __restrict__ flags, __amdgpu_buffer_rsrc_t hrs,
    const unsigned short* Bst,
    float bih_r, float bih_z, float bih_n,
    float bhh_r, float bhh_z, float bhh_n, float bdv,
    int tid, int bt, int j, int b0, int g0)
{
    const int w = tid >> 6, ln = tid & 63;
    const int m = w;                       // 16-row slice 0..3
    const int cc = ln & 15, qq = ln >> 4;
    const int arow = b0 + (m << 4) + cc;   // 16 DISTINCT rows per wave
    const int rowBase = (arow * Hsz + (qq << 3)) << 1;   // bytes
    unsigned* myflag = flag_ptr(flags, bt, m, j);
    unsigned* gateP  = flag_ptr(flags, bt, m, ln & 31);  // lane->producer flag
    const int vcol = (j << 4) + cc;

    float hk[4] = {0.f, 0.f, 0.f, 0.f};

    for (int i = 0; i <= Tsz; ++i) {
        if (FAST) asm volatile("buffer_inv" ::: "memory");   // drop stale L1 lines
        // x for THIS step straight to regs (issued before gate; completes under it)
        float xreg[8];
        if (i < Tsz) {
            #pragma unroll
            for (int e = 0; e < 8; ++e) {
                int k = (qq << 3) + e;
                xreg[e] = (k < Vsz) ? x[(size_t)arow * TV + (size_t)i * Vsz + k] : 0.f;
            }
        }

        // ---- ONE ballot-gate for the whole step: 32 lanes poll 32 producer
        // flags in a single vector gather; busy-spin (activity keeps clocks up)
        for (;;) {
            unsigned v = __hip_atomic_load(gateP, __ATOMIC_RELAXED, __HIP_MEMORY_SCOPE_AGENT);
            if (__all((int)v >= i)) break;
        }

        const int voffA0 = (i & 1) * (3 * BH * 2) + rowBase;

        // ---- issue ALL 48 A-loads upfront (one exposed latency) ----
        s16x8 A1s[16], A2s[16], A3s[16];
        #pragma unroll
        for (int c = 0; c < 16; ++c) {
            A1s[c] = loadA<FAST>(hrs, voffA0 + c * 64);
            A2s[c] = loadA<FAST>(hrs, voffA0 + c * 64 + BH * 2);
            A3s[c] = loadA<FAST>(hrs, voffA0 + c * 64 + 2 * BH * 2);
        }

        f32x4 accR = {0,0,0,0}, accZ = {0,0,0,0}, accNh = {0,0,0,0};
        f32x4 accNi = {0,0,0,0}, accD = {0,0,0,0};

        #pragma unroll
        for (int c = 0; c < 16; ++c) {
            const unsigned short* bs = Bst + (size_t)(c * 9) * 512 + (ln << 3);
            s16x8 R1 = *(const s16x8*)(bs);
            s16x8 R2 = *(const s16x8*)(bs + 512);
            s16x8 R3 = *(const s16x8*)(bs + 1024);
            s16x8 Z1 = *(const s16x8*)(bs + 1536);
            s16x8 Z2 = *(const s16x8*)(bs + 2048);
            s16x8 Z3 = *(const s16x8*)(bs + 2560);
            s16x8 N1 = *(const s16x8*)(bs + 3072);
            s16x8 N2 = *(const s16x8*)(bs + 3584);
            s16x8 N3 = *(const s16x8*)(bs + 4096);
            TRI6(accR, accZ, accNh, R1,R2,R3, Z1,Z2,Z3, N1,N2,N3,
                 A1s[c], A2s[c], A3s[c]);
            if (j < 2) {   // fused decode of h_i
                s16x8 D1 = *(const s16x8*)(Dstg + (size_t)((j << 4) + c) * 512 + (ln << 3));
                accD = MFMA(A1s[c], D1, accD, 0, 0, 0);
                accD = MFMA(A2s[c], D1, accD, 0, 0, 0);
            }
        }

        // x-fold: triple-split fp32 x from regs, 2-plane W from global stream
        if (i < Tsz) {
            s16x8 A1, A2, A3;
            #pragma unroll
            for (int e = 0; e < 8; ++e) {
                float v = xreg[e];
                unsigned short s1 = btrunc(v); float r1 = v - bup(s1);
                unsigned short s2 = btrunc(r1); float r2 = r1 - bup(s2);
                unsigned short s3 = btrunc(r2);
                A1[e] = (short)s1; A2[e] = (short)s2; A3[e] = (short)s3;
            }
            const unsigned short* wr = Wxg + (size_t)(g0 + cc) * 64 + (qq << 3);
            const unsigned short* wz = Wxg + (size_t)(Hsz + g0 + cc) * 64 + (qq << 3);
            const unsigned short* wn = Wxg + (size_t)(2 * Hsz + g0 + cc) * 64 + (qq << 3);
            s16x8 Br1 = *(const s16x8*)(wr), Br2 = *(const s16x8*)(wr + 32);
            s16x8 Bz1 = *(const s16x8*)(wz), Bz2 = *(const s16x8*)(wz + 32);
            s16x8 Bn1 = *(const s16x8*)(wn), Bn2 = *(const s16x8*)(wn + 32);
            TRI5(accR, accZ, accNi, Br1,Br2, Bz1,Bz2, Bn1,Bn2, A1, A2, A3);
        }

        // epilogue: rows qq*4+r (all 16 rows covered), col g0+cc
        if (i < Tsz) {
            const int wpar = ((i + 1) & 1) * (3 * BH * 2);
            #pragma unroll
            for (int r = 0; r < 4; ++r) {
                float rv = accR[r] + bih_r + bhh_r;
                float zv = accZ[r] + bih_z + bhh_z;
                float nh = accNh[r] + bhh_n;
                float ni = accNi[r] + bih_n;
                float rg = 1.f / (1.f + expf(-rv));
                float zg = 1.f / (1.f + expf(-zv));
                float ng = tanhf(ni + rg * nh);
                float hv = (1.f - zg) * ng + zg * hk[r];
                hk[r] = hv;
                int brow = b0 + (m << 4) + (qq << 2) + r;
                int e2 = wpar + ((brow * Hsz + g0 + cc) << 1);
                unsigned short s1 = btrunc(hv); float r1 = hv - bup(s1);
                unsigned short s2 = btrunc(r1); float r2 = r1 - bup(s2);
                unsigned short s3 = btrunc(r2);
                storeH<FAST>(hrs, e2, s1);
                storeH<FAST>(hrs, e2 + BH * 2, s2);
                storeH<FAST>(hrs, e2 + 2 * BH * 2, s3);
            }
        }
        if (i < Tsz) {
            // per-wave publish: h stores AND this wave's h_i reads drained
            asm volatile("s_waitcnt vmcnt(0)" ::: "memory");
            if (ln == 0)
                __hip_atomic_store(myflag, (unsigned)(i + 1), __ATOMIC_RELAXED,
                                   __HIP_MEMORY_SCOPE_AGENT);
        }
        // logits[:, i-1, :] from h_i (after publish; off critical path)
        if (i > 0 && j < 2 && vcol < Vsz) {
            #pragma unroll
            for (int r = 0; r < 4; ++r) {
                size_t brow = (size_t)(b0 + (m << 4) + (qq << 2) + r);
                out[brow * TV + (size_t)(i - 1) * Vsz + vcol] = accD[r] + bdv;
            }
        }
    }
}

__global__ __launch_bounds__(NT, 1) void gru_persist(
    const float* __restrict__ x, const float* __restrict__ W_ih,
    const float* __restrict__ W_hh, const float* __restrict__ b_ih,
    const float* __restrict__ b_hh, const float* __restrict__ W_dec,
    const float* __restrict__ b_dec, char* __restrict__ wsb,
    float* __restrict__ out)
{
    __shared__ unsigned short Bst[16 * 9 * 512];   // [c][tile*plane][lane][8] 144KB
    __shared__ int fastFlag;

    unsigned short* hpl = (unsigned short*)wsb;
    unsigned* cbase = (unsigned*)(wsb + WS_CNT);
    unsigned* flags = (unsigned*)(wsb + WS_FLG);
    unsigned short* Dstg = (unsigned short*)(wsb + WS_DSTG);
    unsigned short* Wxg  = (unsigned short*)(wsb + WS_WXG);

    const int tid = threadIdx.x;
    const int bt  = blockIdx.x & 7;     // group == XCD if round-robin holds
    const int j   = blockIdx.x >> 3;    // 0..31 (16 h' cols)
    const int b0  = bt * 64;
    const int g0  = j * 16;
    unsigned* pcnt  = cbase + 16 + bt;        // consensus barrier counter
    unsigned* xmask = cbase + 32 + bt;        // XCD-id mask

    // ---- one-time: B-stream (triple-split W_hh, fragment-linear) ----
    for (int idx = tid; idx < 16 * 9 * 512; idx += NT) {
        int e = idx & 7, ln2 = (idx >> 3) & 63, s = idx >> 9;
        int p = s % 3, t = (s / 3) % 3, c = s / 9;
        int cc2 = ln2 & 15, qq2 = ln2 >> 4;
        int k = c * 32 + qq2 * 8 + e;
        int grow = t * Hsz + g0 + cc2;
        float v = W_hh[(size_t)grow * Hsz + k];
        unsigned short t1 = btrunc(v); float r1 = v - bup(t1);
        unsigned short t2 = btrunc(r1); float r2 = r1 - bup(t2);
        unsigned short t3 = btrunc(r2);
        Bst[idx] = (p == 0) ? t1 : (p == 1) ? t2 : t3;
    }
    // ---- XCD consensus: fast path iff whole group on one XCD ----
    if (tid == 0) {
        unsigned xcc;
        asm volatile("s_getreg_b32 %0, hwreg(20, 0, 32)" : "=s"(xcc));
        __hip_atomic_fetch_or(xmask, 1u << (xcc & 31), __ATOMIC_RELAXED,
                              __HIP_MEMORY_SCOPE_AGENT);
        asm volatile("s_waitcnt vmcnt(0)" ::: "memory");
    }
    group_barrier(pcnt, JB);
    if (tid == 0) {
        unsigned f = __hip_atomic_load(xmask, __ATOMIC_RELAXED, __HIP_MEMORY_SCOPE_AGENT);
        fastFlag = (__popc(f) == 1) ? 1 : 0;
    }
    __syncthreads();   // Bst ready + consensus decided (last sync before loop)
    const bool fastv = (fastFlag != 0);

    const int cc = tid & 15;
    const float bih_r = b_ih[g0 + cc];
    const float bih_z = b_ih[Hsz + g0 + cc];
    const float bih_n = b_ih[2 * Hsz + g0 + cc];
    const float bhh_r = b_hh[g0 + cc];
    const float bhh_z = b_hh[Hsz + g0 + cc];
    const float bhh_n = b_hh[2 * Hsz + g0 + cc];
    const int vcol = (j << 4) + cc;
    const float bdv = (j < 2 && vcol < Vsz) ? b_dec[vcol] : 0.f;
    __amdgpu_buffer_rsrc_t hrs = make_rsrc((void*)hpl, (unsigned)(2u * 3u * BH * 2u));

    if (fastv)
        gru_loop<true>(x, out, Dstg, Wxg, flags, hrs, Bst,
                       bih_r, bih_z, bih_n, bhh_r, bhh_z, bhh_n, bdv,
                       tid, bt, j, b0, g0);
    else
        gru_loop<false>(x, out, Dstg, Wxg, flags, hrs, Bst,
                        bih_r, bih_z, bih_n, bhh_r, bhh_z, bhh_n, bdv,
                        tid, bt, j, b0, g0);
}

extern "C" void kernel_launch(void* const* d_in, const int* in_sizes, int n_in,
                              void* d_out, int out_size, void* d_ws, size_t ws_size,
                              hipStream_t stream) {
    const float* x     = (const float*)d_in[0];
    const float* W_ih  = (const float*)d_in[1];
    const float* W_hh  = (const float*)d_in[2];
    const float* b_ih  = (const float*)d_in[3];
    const float* b_hh  = (const float*)d_in[4];
    const float* W_dec = (const float*)d_in[5];
    const float* b_dec = (const float*)d_in[6];
    float* out = (float*)d_out;
    char* wsb  = (char*)d_ws;

    init_ws_kernel<<<768, 256, 0, stream>>>(
        (unsigned short*)wsb, (unsigned*)(wsb + WS_CNT),
        (unsigned short*)(wsb + WS_DSTG), (unsigned short*)(wsb + WS_WXG),
        W_ih, W_dec);

    // Plain launch: 144 KB LDS -> 1 block/CU, grid == 256 == CU count ->
    // all blocks co-resident. Per-wave producer-flag dataflow cannot
    // deadlock: flags monotonic, every wave publishes after every step
    // (induction: step-i gates need only step-(i-1) publishes).
    gru_persist<<<dim3(NBLK), dim3(NT), 0, stream>>>(
        x, W_ih, W_hh, b_ih, b_hh, W_dec, b_dec, wsb, out);
}

// Round 19
// 11694.572 us; speedup vs baseline: 1.3267x; 1.0283x over previous
//
#include <hip/hip_runtime.h>
#include <math.h>

#define Bsz 512
#define Tsz 1024
#define Vsz 27
#define Hsz 512
#define BH (Bsz * Hsz)
#define TV (Tsz * Vsz)
#define NBLK 256
#define NT 128       // 2 waves; wave = 32 distinct batch rows (2 A-sets), 3 gates
#define JB 32        // blocks per bt-group

typedef float f32x4 __attribute__((ext_vector_type(4)));
typedef short s16x8 __attribute__((ext_vector_type(8)));
typedef unsigned int u32x4 __attribute__((ext_vector_type(4)));
#define MFMA __builtin_amdgcn_mfma_f32_16x16x32_bf16

// ws byte offsets
#define WS_CNT  ((size_t)2 * 3 * BH * 2)             // consensus counters (4KB)
#define WS_FLG  (WS_CNT + 4096)                      // 128KB per-wave flags
#define WS_DSTG (WS_FLG + 262144)                    // 32KB decode stream
#define WS_WXG  (WS_DSTG + (size_t)2 * 16 * 512 * 2) // 192KB x-fold W stream

__device__ __forceinline__ unsigned short btrunc(float x) {   // bf16 RTZ bits
    return (unsigned short)(__float_as_uint(x) >> 16);
}
__device__ __forceinline__ float bup(unsigned short b) {
    return __uint_as_float(((unsigned)b) << 16);
}
__device__ __forceinline__ unsigned short brne(float x) {     // bf16 RNE bits
    unsigned u = __float_as_uint(x);
    return (unsigned short)((u + 0x7FFFu + ((u >> 16) & 1u)) >> 16);
}
__device__ __forceinline__ __amdgpu_buffer_rsrc_t make_rsrc(void* p, unsigned bytes) {
    return __builtin_amdgcn_make_buffer_rsrc(p, (short)0, (int)bytes, 0x00020000);
}
template<bool FAST>
__device__ __forceinline__ s16x8 loadA(__amdgpu_buffer_rsrc_t r, int off) {
    u32x4 d = __builtin_amdgcn_raw_buffer_load_b128(r, off, 0, FAST ? 0 : 0x11);
    return __builtin_bit_cast(s16x8, d);
}
template<bool FAST>
__device__ __forceinline__ void storeH(__amdgpu_buffer_rsrc_t r, int off, unsigned short v) {
    __builtin_amdgcn_raw_buffer_store_b16(v, r, off, 0, FAST ? 0 : 0x11);
}
// per-wave flags (128B-strided): (bt,m,j) -> slot. PROVEN __hip_atomic_* only.
__device__ __forceinline__ unsigned* flag_ptr(unsigned* flags, int bt, int m, int jp) {
    return flags + (size_t)((((bt << 2) + m) << 5) + jp) * 32;
}

// Interleaved 6-product triple-split for 3 gates: per-accumulator order is
// A1B1,A1B2,A2B1,A1B3,A2B2,A3B1 — identical to R7-R18's proven PROD6.
#define TRI6(AR, AZ, AN, R1,R2,R3, Z1,Z2,Z3, N1,N2,N3, A1_,A2_,A3_) do { \
    AR = MFMA(A1_, R1, AR,0,0,0); AZ = MFMA(A1_, Z1, AZ,0,0,0); AN = MFMA(A1_, N1, AN,0,0,0); \
    AR = MFMA(A1_, R2, AR,0,0,0); AZ = MFMA(A1_, Z2, AZ,0,0,0); AN = MFMA(A1_, N2, AN,0,0,0); \
    AR = MFMA(A2_, R1, AR,0,0,0); AZ = MFMA(A2_, Z1, AZ,0,0,0); AN = MFMA(A2_, N1, AN,0,0,0); \
    AR = MFMA(A1_, R3, AR,0,0,0); AZ = MFMA(A1_, Z3, AZ,0,0,0); AN = MFMA(A1_, N3, AN,0,0,0); \
    AR = MFMA(A2_, R2, AR,0,0,0); AZ = MFMA(A2_, Z2, AZ,0,0,0); AN = MFMA(A2_, N2, AN,0,0,0); \
    AR = MFMA(A3_, R1, AR,0,0,0); AZ = MFMA(A3_, Z1, AZ,0,0,0); AN = MFMA(A3_, N1, AN,0,0,0); \
} while (0)
#define TRI5(AR, AZ, AN, R1,R2, Z1,Z2, N1,N2, A1_,A2_,A3_) do { \
    AR = MFMA(A1_, R1, AR,0,0,0); AZ = MFMA(A1_, Z1, AZ,0,0,0); AN = MFMA(A1_, N1, AN,0,0,0); \
    AR = MFMA(A1_, R2, AR,0,0,0); AZ = MFMA(A1_, Z2, AZ,0,0,0); AN = MFMA(A1_, N2, AN,0,0,0); \
    AR = MFMA(A2_, R1, AR,0,0,0); AZ = MFMA(A2_, Z1, AZ,0,0,0); AN = MFMA(A2_, N1, AN,0,0,0); \
    AR = MFMA(A2_, R2, AR,0,0,0); AZ = MFMA(A2_, Z2, AZ,0,0,0); AN = MFMA(A2_, N2, AN,0,0,0); \
    AR = MFMA(A3_, R1, AR,0,0,0); AZ = MFMA(A3_, Z1, AZ,0,0,0); AN = MFMA(A3_, N1, AN,0,0,0); \
} while (0)

__global__ void init_ws_kernel(unsigned short* __restrict__ hpl, unsigned* __restrict__ cntr,
                               unsigned short* __restrict__ Dstg, unsigned short* __restrict__ Wxg,
                               const float* __restrict__ W_ih, const float* __restrict__ W_dec)
{
    size_t gid = (size_t)blockIdx.x * 256 + threadIdx.x;
    size_t gsz = (size_t)gridDim.x * 256;
    for (size_t i = gid; i < (size_t)(2 * 3 * BH * 2) / 16; i += gsz)
        ((uint4*)hpl)[i] = make_uint4(0u, 0u, 0u, 0u);
    // zero consensus counters + per-wave flags (4KB + 128KB)
    for (size_t i = gid; i < 33792; i += gsz) cntr[i] = 0u;
    // decode stream [jj:2][c:16][lane:64][8]
    for (size_t i = gid; i < 2 * 16 * 512; i += gsz) {
        int e = i & 7, ln2 = (i >> 3) & 63, c = (i >> 9) & 15, jj = (int)(i >> 13);
        int cc2 = ln2 & 15, qq2 = ln2 >> 4;
        int k = c * 32 + qq2 * 8 + e;
        int vr = jj * 16 + cc2;
        Dstg[i] = (vr < Vsz) ? brne(W_dec[(size_t)vr * Hsz + k]) : (unsigned short)0;
    }
    // x-fold W stream [grow:1536][p:2][k:32]
    for (size_t i = gid; i < 1536 * 64; i += gsz) {
        int k = i & 31, p = (i >> 5) & 1, grow = (int)(i >> 6);
        float v = (k < Vsz) ? W_ih[grow * Vsz + k] : 0.f;
        unsigned short t1 = btrunc(v); float r1 = v - bup(t1);
        unsigned short t2 = btrunc(r1);
        Wxg[i] = p ? t2 : t1;
    }
}

// atomic group barrier — used ONCE for the XCD-consensus pre-barrier (proven)
__device__ __forceinline__ void group_barrier(unsigned* c, unsigned target) {
    __syncthreads();
    if (threadIdx.x == 0) {
        __hip_atomic_fetch_add(c, 1u, __ATOMIC_RELAXED, __HIP_MEMORY_SCOPE_AGENT);
        while (__hip_atomic_load(c, __ATOMIC_RELAXED, __HIP_MEMORY_SCOPE_AGENT) < target)
            __builtin_amdgcn_s_sleep(2);
    }
    __syncthreads();
}

// Wave-autonomous chain: 32 distinct batch rows (2 A-sets) x 16 h' cols, 3 gates.
// Each B fragment read from LDS feeds 36 MFMAs (2x R18) -> LDS traffic halved.
template<bool FAST>
__device__ __forceinline__ void gru_loop(
    const float* __restrict__ x, float* __restrict__ out,
    const unsigned short* __restrict__ Dstg, const unsigned short* __restrict__ Wxg,
    unsigned* __restrict__ flags, __amdgpu_buffer_rsrc_t hrs,
    const unsigned short* Bst,
    float bih_r, float bih_z, float bih_n,
    float bhh_r, float bhh_z, float bhh_n, float bdv,
    int tid, int bt, int j, int b0, int g0)
{
    const int w = tid >> 6, ln = tid & 63;
    const int m = w;                       // 32-row slice 0..1
    const int cc = ln & 15, qq = ln >> 4;
    const int ar0 = b0 + (m << 5) + cc;    // A-set 0: rows 0-15 of slice
    const int ar1 = ar0 + 16;              // A-set 1: rows 16-31 of slice
    const int rb0 = (ar0 * Hsz + (qq << 3)) << 1;   // bytes
    const int rb1 = (ar1 * Hsz + (qq << 3)) << 1;
    unsigned* myflag = flag_ptr(flags, bt, m, j);
    unsigned* gateP  = flag_ptr(flags, bt, m, ln & 31);  // lane->producer flag
    const int vcol = (j << 4) + cc;

    float hk0[4] = {0.f, 0.f, 0.f, 0.f};
    float hk1[4] = {0.f, 0.f, 0.f, 0.f};

    for (int i = 0; i <= Tsz; ++i) {
        if (FAST) asm volatile("buffer_inv" ::: "memory");   // drop stale L1 lines
        // x for THIS step straight to regs (issued before gate; completes under it)
        float xr0[8], xr1[8];
        if (i < Tsz) {
            #pragma unroll
            for (int e = 0; e < 8; ++e) {
                int k = (qq << 3) + e;
                xr0[e] = (k < Vsz) ? x[(size_t)ar0 * TV + (size_t)i * Vsz + k] : 0.f;
                xr1[e] = (k < Vsz) ? x[(size_t)ar1 * TV + (size_t)i * Vsz + k] : 0.f;
            }
        }

        // ---- ONE ballot-gate per step: 32 lanes poll 32 producer flags ----
        for (;;) {
            unsigned v = __hip_atomic_load(gateP, __ATOMIC_RELAXED, __HIP_MEMORY_SCOPE_AGENT);
            if (__all((int)v >= i)) break;
        }

        const int par = (i & 1) * (3 * BH * 2);
        const int vA0 = par + rb0, vA1 = par + rb1;

        f32x4 aR0 = {0,0,0,0}, aZ0 = {0,0,0,0}, aNh0 = {0,0,0,0};
        f32x4 aR1 = {0,0,0,0}, aZ1 = {0,0,0,0}, aNh1 = {0,0,0,0};
        f32x4 aNi0 = {0,0,0,0}, aNi1 = {0,0,0,0};
        f32x4 aD0 = {0,0,0,0}, aD1 = {0,0,0,0};

        // 1-chunk-ahead A prefetch pipeline (R16-proven), 2 row-sets
        s16x8 Pa1[2], Pa2[2], Pa3[2], Pb1[2], Pb2[2], Pb3[2];
        Pa1[0] = loadA<FAST>(hrs, vA0);
        Pa2[0] = loadA<FAST>(hrs, vA0 + BH * 2);
        Pa3[0] = loadA<FAST>(hrs, vA0 + 2 * BH * 2);
        Pb1[0] = loadA<FAST>(hrs, vA1);
        Pb2[0] = loadA<FAST>(hrs, vA1 + BH * 2);
        Pb3[0] = loadA<FAST>(hrs, vA1 + 2 * BH * 2);
        #pragma unroll
        for (int c = 0; c < 16; ++c) {
            const int cur = c & 1, nxt = cur ^ 1;
            if (c < 15) {
                Pa1[nxt] = loadA<FAST>(hrs, vA0 + (c + 1) * 64);
                Pa2[nxt] = loadA<FAST>(hrs, vA0 + (c + 1) * 64 + BH * 2);
                Pa3[nxt] = loadA<FAST>(hrs, vA0 + (c + 1) * 64 + 2 * BH * 2);
                Pb1[nxt] = loadA<FAST>(hrs, vA1 + (c + 1) * 64);
                Pb2[nxt] = loadA<FAST>(hrs, vA1 + (c + 1) * 64 + BH * 2);
                Pb3[nxt] = loadA<FAST>(hrs, vA1 + (c + 1) * 64 + 2 * BH * 2);
            }
            const unsigned short* bs = Bst + (size_t)(c * 9) * 512 + (ln << 3);
            s16x8 R1 = *(const s16x8*)(bs);
            s16x8 R2 = *(const s16x8*)(bs + 512);
            s16x8 R3 = *(const s16x8*)(bs + 1024);
            s16x8 Z1 = *(const s16x8*)(bs + 1536);
            s16x8 Z2 = *(const s16x8*)(bs + 2048);
            s16x8 Z3 = *(const s16x8*)(bs + 2560);
            s16x8 N1 = *(const s16x8*)(bs + 3072);
            s16x8 N2 = *(const s16x8*)(bs + 3584);
            s16x8 N3 = *(const s16x8*)(bs + 4096);
            TRI6(aR0, aZ0, aNh0, R1,R2,R3, Z1,Z2,Z3, N1,N2,N3,
                 Pa1[cur], Pa2[cur], Pa3[cur]);
            TRI6(aR1, aZ1, aNh1, R1,R2,R3, Z1,Z2,Z3, N1,N2,N3,
                 Pb1[cur], Pb2[cur], Pb3[cur]);
            if (j < 2) {   // fused decode of h_i, both row-sets (D read once)
                s16x8 D1 = *(const s16x8*)(Dstg + (size_t)((j << 4) + c) * 512 + (ln << 3));
                aD0 = MFMA(Pa1[cur], D1, aD0, 0, 0, 0);
                aD0 = MFMA(Pa2[cur], D1, aD0, 0, 0, 0);
                aD1 = MFMA(Pb1[cur], D1, aD1, 0, 0, 0);
                aD1 = MFMA(Pb2[cur], D1, aD1, 0, 0, 0);
            }
        }

        // x-fold: triple-split fp32 x from regs, 2-plane W from global stream
        if (i < Tsz) {
            const unsigned short* wr = Wxg + (size_t)(g0 + cc) * 64 + (qq << 3);
            const unsigned short* wz = Wxg + (size_t)(Hsz + g0 + cc) * 64 + (qq << 3);
            const unsigned short* wn = Wxg + (size_t)(2 * Hsz + g0 + cc) * 64 + (qq << 3);
            s16x8 Br1 = *(const s16x8*)(wr), Br2 = *(const s16x8*)(wr + 32);
            s16x8 Bz1 = *(const s16x8*)(wz), Bz2 = *(const s16x8*)(wz + 32);
            s16x8 Bn1 = *(const s16x8*)(wn), Bn2 = *(const s16x8*)(wn + 32);
            {
                s16x8 A1, A2, A3;
                #pragma unroll
                for (int e = 0; e < 8; ++e) {
                    float v = xr0[e];
                    unsigned short s1 = btrunc(v); float r1 = v - bup(s1);
                    unsigned short s2 = btrunc(r1); float r2 = r1 - bup(s2);
                    unsigned short s3 = btrunc(r2);
                    A1[e] = (short)s1; A2[e] = (short)s2; A3[e] = (short)s3;
                }
                TRI5(aR0, aZ0, aNi0, Br1,Br2, Bz1,Bz2, Bn1,Bn2, A1, A2, A3);
            }
            {
                s16x8 A1, A2, A3;
                #pragma unroll
                for (int e = 0; e < 8; ++e) {
                    float v = xr1[e];
                    unsigned short s1 = btrunc(v); float r1 = v - bup(s1);
                    unsigned short s2 = btrunc(r1); float r2 = r1 - bup(s2);
                    unsigned short s3 = btrunc(r2);
                    A1[e] = (short)s1; A2[e] = (short)s2; A3[e] = (short)s3;
                }
                TRI5(aR1, aZ1, aNi1, Br1,Br2, Bz1,Bz2, Bn1,Bn2, A1, A2, A3);
            }
        }

        // epilogue: both row-sets; rows qq*4+r within each 16-row set
        if (i < Tsz) {
            const int wpar = ((i + 1) & 1) * (3 * BH * 2);
            #pragma unroll
            for (int r = 0; r < 4; ++r) {
                {   // set 0
                    float rv = aR0[r] + bih_r + bhh_r;
                    float zv = aZ0[r] + bih_z + bhh_z;
                    float nh = aNh0[r] + bhh_n;
                    float ni = aNi0[r] + bih_n;
                    float rg = 1.f / (1.f + expf(-rv));
                    float zg = 1.f / (1.f + expf(-zv));
                    float ng = tanhf(ni + rg * nh);
                    float hv = (1.f - zg) * ng + zg * hk0[r];
                    hk0[r] = hv;
                    int brow = b0 + (m << 5) + (qq << 2) + r;
                    int e2 = wpar + ((brow * Hsz + g0 + cc) << 1);
                    unsigned short s1 = btrunc(hv); float r1 = hv - bup(s1);
                    unsigned short s2 = btrunc(r1); float r2 = r1 - bup(s2);
                    unsigned short s3 = btrunc(r2);
                    storeH<FAST>(hrs, e2, s1);
                    storeH<FAST>(hrs, e2 + BH * 2, s2);
                    storeH<FAST>(hrs, e2 + 2 * BH * 2, s3);
                }
                {   // set 1
                    float rv = aR1[r] + bih_r + bhh_r;
                    float zv = aZ1[r] + bih_z + bhh_z;
                    float nh = aNh1[r] + bhh_n;
                    float ni = aNi1[r] + bih_n;
                    float rg = 1.f / (1.f + expf(-rv));
                    float zg = 1.f / (1.f + expf(-zv));
                    float ng = tanhf(ni + rg * nh);
                    float hv = (1.f - zg) * ng + zg * hk1[r];
                    hk1[r] = hv;
                    int brow = b0 + (m << 5) + 16 + (qq << 2) + r;
                    int e2 = wpar + ((brow * Hsz + g0 + cc) << 1);
                    unsigned short s1 = btrunc(hv); float r1 = hv - bup(s1);
                    unsigned short s2 = btrunc(r1); float r2 = r1 - bup(s2);
                    unsigned short s3 = btrunc(r2);
                    storeH<FAST>(hrs, e2, s1);
                    storeH<FAST>(hrs, e2 + BH * 2, s2);
                    storeH<FAST>(hrs, e2 + 2 * BH * 2, s3);
                }
            }
        }
        if (i < Tsz) {
            // per-wave publish: h stores AND this wave's h_i reads drained
            asm volatile("s_waitcnt vmcnt(0)" ::: "memory");
            if (ln == 0)
                __hip_atomic_store(myflag, (unsigned)(i + 1), __ATOMIC_RELAXED,
                                   __HIP_MEMORY_SCOPE_AGENT);
        }
        // logits[:, i-1, :] from h_i (after publish; off critical path)
        if (i > 0 && j < 2 && vcol < Vsz) {
            #pragma unroll
            for (int r = 0; r < 4; ++r) {
                size_t br0 = (size_t)(b0 + (m << 5) + (qq << 2) + r);
                size_t br1 = br0 + 16;
                out[br0 * TV + (size_t)(i - 1) * Vsz + vcol] = aD0[r] + bdv;
                out[br1 * TV + (size_t)(i - 1) * Vsz + vcol] = aD1[r] + bdv;
            }
        }
    }
}

__global__ __launch_bounds__(NT, 1) void gru_persist(
    const float* __restrict__ x, const float* __restrict__ W_ih,
    const float* __restrict__ W_hh, const float* __restrict__ b_ih,
    const float* __restrict__ b_hh, const float* __restrict__ W_dec,
    const float* __restrict__ b_dec, char* __restrict__ wsb,
    float* __restrict__ out)
{
    __shared__ unsigned short Bst[16 * 9 * 512];   // [c][tile*plane][lane][8] 144KB
    __shared__ int fastFlag;

    unsigned short* hpl = (unsigned short*)wsb;
    unsigned* cbase = (unsigned*)(wsb + WS_CNT);
    unsigned* flags = (unsigned*)(wsb + WS_FLG);
    unsigned short* Dstg = (unsigned short*)(wsb + WS_DSTG);
    unsigned short* Wxg  = (unsigned short*)(wsb + WS_WXG);

    const int tid = threadIdx.x;
    const int bt  = blockIdx.x & 7;     // group == XCD if round-robin holds
    const int j   = blockIdx.x >> 3;    // 0..31 (16 h' cols)
    const int b0  = bt * 64;
    const int g0  = j * 16;
    unsigned* pcnt  = cbase + 16 + bt;        // consensus barrier counter
    unsigned* xmask = cbase + 32 + bt;        // XCD-id mask

    // ---- one-time: B-stream (triple-split W_hh, fragment-linear) ----
    for (int idx = tid; idx < 16 * 9 * 512; idx += NT) {
        int e = idx & 7, ln2 = (idx >> 3) & 63, s = idx >> 9;
        int p = s % 3, t = (s / 3) % 3, c = s / 9;
        int cc2 = ln2 & 15, qq2 = ln2 >> 4;
        int k = c * 32 + qq2 * 8 + e;
        int grow = t * Hsz + g0 + cc2;
        float v = W_hh[(size_t)grow * Hsz + k];
        unsigned short t1 = btrunc(v); float r1 = v - bup(t1);
        unsigned short t2 = btrunc(r1); float r2 = r1 - bup(t2);
        unsigned short t3 = btrunc(r2);
        Bst[idx] = (p == 0) ? t1 : (p == 1) ? t2 : t3;
    }
    // ---- XCD consensus: fast path iff whole group on one XCD ----
    if (tid == 0) {
        unsigned xcc;
        asm volatile("s_getreg_b32 %0, hwreg(20, 0, 32)" : "=s"(xcc));
        __hip_atomic_fetch_or(xmask, 1u << (xcc & 31), __ATOMIC_RELAXED,
                              __HIP_MEMORY_SCOPE_AGENT);
        asm volatile("s_waitcnt vmcnt(0)" ::: "memory");
    }
    group_barrier(pcnt, JB);
    if (tid == 0) {
        unsigned f = __hip_atomic_load(xmask, __ATOMIC_RELAXED, __HIP_MEMORY_SCOPE_AGENT);
        fastFlag = (__popc(f) == 1) ? 1 : 0;
    }
    __syncthreads();   // Bst ready + consensus decided (last sync before loop)
    const bool fastv = (fastFlag != 0);

    const int cc = tid & 15;
    const float bih_r = b_ih[g0 + cc];
    const float bih_z = b_ih[Hsz + g0 + cc];
    const float bih_n = b_ih[2 * Hsz + g0 + cc];
    const float bhh_r = b_hh[g0 + cc];
    const float bhh_z = b_hh[Hsz + g0 + cc];
    const float bhh_n = b_hh[2 * Hsz + g0 + cc];
    const int vcol = (j << 4) + cc;
    const float bdv = (j < 2 && vcol < Vsz) ? b_dec[vcol] : 0.f;
    __amdgpu_buffer_rsrc_t hrs = make_rsrc((void*)hpl, (unsigned)(2u * 3u * BH * 2u));

    if (fastv)
        gru_loop<true>(x, out, Dstg, Wxg, flags, hrs, Bst,
                       bih_r, bih_z, bih_n, bhh_r, bhh_z, bhh_n, bdv,
                       tid, bt, j, b0, g0);
    else
        gru_loop<false>(x, out, Dstg, Wxg, flags, hrs, Bst,
                        bih_r, bih_z, bih_n, bhh_r, bhh_z, bhh_n, bdv,
                        tid, bt, j, b0, g0);
}

extern "C" void kernel_launch(void* const* d_in, const int* in_sizes, int n_in,
                              void* d_out, int out_size, void* d_ws, size_t ws_size,
                              hipStream_t stream) {
    const float* x     = (const float*)d_in[0];
    const float* W_ih  = (const float*)d_in[1];
    const float* W_hh  = (const float*)d_in[2];
    const float* b_ih  = (const float*)d_in[3];
    const float* b_hh  = (const float*)d_in[4];
    const float* W_dec = (const float*)d_in[5];
    const float* b_dec = (const float*)d_in[6];
    float* out = (float*)d_out;
    char* wsb  = (char*)d_ws;

    init_ws_kernel<<<768, 256, 0, stream>>>(
        (unsigned short*)wsb, (unsigned*)(wsb + WS_CNT),
        (unsigned short*)(wsb + WS_DSTG), (unsigned short*)(wsb + WS_WXG),
        W_ih, W_dec);

    // Plain launch: 144 KB LDS -> 1 block/CU, grid == 256 == CU count ->
    // all blocks co-resident. Per-wave producer-flag dataflow cannot
    // deadlock: flags monotonic, every wave publishes after every step
    // (induction: step-i gates need only step-(i-1) publishes).
    gru_persist<<<dim3(NBLK), dim3(NT), 0, stream>>>(
        x, W_ih, W_hh, b_ih, b_hh, W_dec, b_dec, wsb, out);
}